// Round 10
// baseline (937.817 us; speedup 1.0000x reference)
//
#include <hip/hip_runtime.h>
#include <hip/hip_bf16.h>
#include <cstddef>

// Problem constants
#define BB    256
#define TT    512
#define DIN   64
#define H1    256
#define INTER 128
#define STATE 256
#define MOTOR 64
#define DOUT  32
#define BT    (BB*TT)   // 131072

typedef unsigned int u32;
typedef short short8 __attribute__((ext_vector_type(8)));
typedef float f32x4  __attribute__((ext_vector_type(4)));

// Packed-weight (hi/lo bf16 in one u32) fragment-order offsets, in u32 elems
#define OFF_I1 0         // Wi1: 64x256   -> 16384
#define OFF_I2 16384     // Wi2: 256x256  -> 65536
#define OFF_I3 81920     // Wi3: 256x128  -> 32768
#define OFF_IH 114688    // Wih: 128x256  -> 32768
#define OFF_O1 147456    // Wo1: 64x256   -> 16384
#define OFF_O2 163840    // Wo2: 256x256  -> 65536
#define OFF_O3 229376    // Wo3: 256x32   -> 8192
#define BPK_TOTAL 237568

__device__ __forceinline__ float tanh_fast(float x) {
    float e = __expf(2.0f * x);
    return 1.0f - 2.0f / (e + 1.0f);
}

__device__ __forceinline__ u32 f2u(float f){ union{float f; u32 u;} v; v.f=f; return v.u; }
__device__ __forceinline__ float u2f(u32 u){ union{u32 u; float f;} v; v.u=u; return v.f; }

// fp32 -> packed (hi bf16 in [15:0], residual-lo bf16 in [31:16]), RNE both.
__device__ __forceinline__ u32 packhl(float x) {
    u32 b  = f2u(x);
    u32 hi = (b + 0x7fffu + ((b >> 16) & 1u)) >> 16;
    float lo = x - u2f(hi << 16);
    u32 bl = f2u(lo);
    u32 l16 = (bl + 0x7fffu + ((bl >> 16) & 1u)) >> 16;
    return (hi & 0xffffu) | (l16 << 16);
}

// 8 packed u32 -> hi-frag / lo-frag (each 8 bf16 as short8)
__device__ __forceinline__ void unpack8(uint4 w0, uint4 w1, short8& hi, short8& lo) {
    union { u32 u[4]; short8 s; } H, L;
    H.u[0] = __builtin_amdgcn_perm(w0.y, w0.x, 0x05040100u);
    L.u[0] = __builtin_amdgcn_perm(w0.y, w0.x, 0x07060302u);
    H.u[1] = __builtin_amdgcn_perm(w0.w, w0.z, 0x05040100u);
    L.u[1] = __builtin_amdgcn_perm(w0.w, w0.z, 0x07060302u);
    H.u[2] = __builtin_amdgcn_perm(w1.y, w1.x, 0x05040100u);
    L.u[2] = __builtin_amdgcn_perm(w1.y, w1.x, 0x07060302u);
    H.u[3] = __builtin_amdgcn_perm(w1.w, w1.z, 0x05040100u);
    L.u[3] = __builtin_amdgcn_perm(w1.w, w1.z, 0x07060302u);
    hi = H.s; lo = L.s;
}

// LDS activation addressing: [64 rows][256 words], XOR-swizzled in 16B units.
__device__ __forceinline__ int swz(int row, int col) {
    return row * 256 + (col ^ ((row & 7) << 2));
}

// ---------------------------------------------------------------------------
// One MFMA MLP layer over a 64-token tile held in LDS (packed hi/lo u32).
//   Split-bf16: D += Ahi*Bhi + Ahi*Blo + Alo*Bhi  (~fp32 accuracy).
// ---------------------------------------------------------------------------
template<int K, int N, bool TANH, bool TOGLOBAL>
__device__ __forceinline__ void mfma_layer(
    const u32* __restrict__ Bpk, const float* __restrict__ bias,
    const u32* inB, u32* outB, float* __restrict__ gout,
    int lane, int wv)
{
    constexpr int NF  = N / 16;
    constexpr int NFW = (NF >= 4) ? NF / 4 : 1;
    constexpr int KC  = K / 32;
    const int q = lane >> 4, c = lane & 15;
    const int nf0 = wv * NFW;
    if (nf0 >= NF) return;   // small-N layers idle the upper waves

    f32x4 acc[4][NFW];
    #pragma unroll
    for (int nf = 0; nf < NFW; ++nf) {
        float bv = bias[(nf0 + nf) * 16 + c];
        #pragma unroll
        for (int rf = 0; rf < 4; ++rf) acc[rf][nf] = (f32x4){bv, bv, bv, bv};
    }

    #pragma unroll 2
    for (int kc = 0; kc < KC; ++kc) {
        short8 ahi[4], alo[4];
        #pragma unroll
        for (int rf = 0; rf < 4; ++rf) {
            int row = rf * 16 + c;
            int kb  = kc * 32 + q * 8;
            int m4  = (row & 7) << 2;
            uint4 w0 = *(const uint4*)(inB + row * 256 + ( kb      ^ m4));
            uint4 w1 = *(const uint4*)(inB + row * 256 + ((kb + 4) ^ m4));
            unpack8(w0, w1, ahi[rf], alo[rf]);
        }
        #pragma unroll
        for (int nf = 0; nf < NFW; ++nf) {
            const u32* bp = Bpk + (((size_t)(kc * NF + nf0 + nf) * 64 + lane) * 8);
            uint4 b0 = *(const uint4*)bp;
            uint4 b1 = *(const uint4*)(bp + 4);
            short8 bhi, blo; unpack8(b0, b1, bhi, blo);
            #pragma unroll
            for (int rf = 0; rf < 4; ++rf) {
                acc[rf][nf] = __builtin_amdgcn_mfma_f32_16x16x32_bf16(ahi[rf], bhi, acc[rf][nf], 0, 0, 0);
                acc[rf][nf] = __builtin_amdgcn_mfma_f32_16x16x32_bf16(ahi[rf], blo, acc[rf][nf], 0, 0, 0);
                acc[rf][nf] = __builtin_amdgcn_mfma_f32_16x16x32_bf16(alo[rf], bhi, acc[rf][nf], 0, 0, 0);
            }
        }
    }

    #pragma unroll
    for (int rf = 0; rf < 4; ++rf) {
        #pragma unroll
        for (int nf = 0; nf < NFW; ++nf) {
            #pragma unroll
            for (int r = 0; r < 4; ++r) {
                float v = acc[rf][nf][r];
                if (TANH) v = tanh_fast(v);
                int row = rf * 16 + q * 4 + r;
                int col = (nf0 + nf) * 16 + c;
                if (TOGLOBAL) gout[(size_t)row * N + col] = v;
                else          outB[swz(row, col)] = packhl(v);
            }
        }
    }
}

// Stage a [64 tokens][64 cols] fp32 global tile into packed LDS (cols 0..63).
__device__ __forceinline__ void stage64(const float* __restrict__ src, u32* dst, int tid) {
    int tt = tid >> 4;
    int c4 = (tid & 15) * 4;
    #pragma unroll
    for (int i = 0; i < 4; ++i) {
        int tok = tt + 16 * i;
        float4 v = *(const float4*)(src + (size_t)tok * 64 + c4);
        uint4 p;
        p.x = packhl(v.x); p.y = packhl(v.y); p.z = packhl(v.z); p.w = packhl(v.w);
        *(uint4*)(dst + swz(tok, c4)) = p;
    }
}

// ---------------------------------------------------------------------------
// prep: pack all MLP weights into MFMA-fragment order (hi/lo u32), and build
// WpT = [Whh^T (256 rows) ; Who^T (64 rows)], each row 256 floats.
// ---------------------------------------------------------------------------
__global__ __launch_bounds__(256) void prep_kernel(
    const float* __restrict__ Wi1, const float* __restrict__ Wi2,
    const float* __restrict__ Wi3, const float* __restrict__ Wih,
    const float* __restrict__ Wo1, const float* __restrict__ Wo2,
    const float* __restrict__ Wo3,
    const float* __restrict__ Whh, const float* __restrict__ Who,
    u32* __restrict__ Bpk, float* __restrict__ WpT)
{
    int idx = blockIdx.x * 256 + threadIdx.x;
    if (idx < BPK_TOTAL) {
        const float* W; int NF; int i = idx;
        if      (i < OFF_I2) { W = Wi1; NF = 16; i -= OFF_I1; }
        else if (i < OFF_I3) { W = Wi2; NF = 16; i -= OFF_I2; }
        else if (i < OFF_IH) { W = Wi3; NF = 8;  i -= OFF_I3; }
        else if (i < OFF_O1) { W = Wih; NF = 16; i -= OFF_IH; }
        else if (i < OFF_O2) { W = Wo1; NF = 16; i -= OFF_O1; }
        else if (i < OFF_O3) { W = Wo2; NF = 16; i -= OFF_O2; }
        else                 { W = Wo3; NF = 2;  i -= OFF_O3; }
        int e = i & 7, l = (i >> 3) & 63, t = i >> 9;
        int nf = t % NF, kc = t / NF;
        int k = kc * 32 + ((l >> 4) * 8) + e;
        int n = nf * 16 + (l & 15);
        Bpk[idx] = packhl(W[(size_t)k * (NF * 16) + n]);
    } else if (idx < BPK_TOTAL + STATE*STATE) {
        int i = idx - BPK_TOTAL; int j = i >> 8, n = i & 255;
        WpT[n * STATE + j] = Whh[j * STATE + n];
    } else if (idx < BPK_TOTAL + STATE*STATE + STATE*MOTOR) {
        int i = idx - BPK_TOTAL - STATE*STATE; int j = i >> 6, o = i & 63;
        WpT[(size_t)(STATE + o) * STATE + j] = Who[j * MOTOR + o];
    }
}

// ---------------------------------------------------------------------------
// MFMA encoder: x -> tanh(Wi1) -> tanh(Wi2) -> Wi3 -> (Wih + bh) = u
// ---------------------------------------------------------------------------
__global__ __launch_bounds__(256, 1) void encoder_mfma(
    const float* __restrict__ x, const u32* __restrict__ Bpk,
    const float* __restrict__ bi1, const float* __restrict__ bi2,
    const float* __restrict__ bi3, const float* __restrict__ bh,
    float* __restrict__ u)
{
    __shared__ u32 buf0[64 * 256];
    __shared__ u32 buf1[64 * 256];
    const int tid = threadIdx.x, lane = tid & 63, wv = tid >> 6;
    const size_t row0 = (size_t)blockIdx.x * 64;

    stage64(x + row0 * DIN, buf0, tid);
    __syncthreads();
    mfma_layer<DIN,  H1,    true,  false>(Bpk + OFF_I1, bi1, buf0, buf1, nullptr, lane, wv);
    __syncthreads();
    mfma_layer<H1,   H1,    true,  false>(Bpk + OFF_I2, bi2, buf1, buf0, nullptr, lane, wv);
    __syncthreads();
    mfma_layer<H1,   INTER, false, false>(Bpk + OFF_I3, bi3, buf0, buf1, nullptr, lane, wv);
    __syncthreads();
    mfma_layer<INTER,STATE, false, true >(Bpk + OFF_IH, bh,  buf1, nullptr, u + row0 * STATE, lane, wv);
}

// ---------------------------------------------------------------------------
// MFMA decoder: m -> tanh(Wo1) -> tanh(Wo2) -> Wo3 -> y
// ---------------------------------------------------------------------------
__global__ __launch_bounds__(256, 1) void decoder_mfma(
    const float* __restrict__ m, const u32* __restrict__ Bpk,
    const float* __restrict__ bo1, const float* __restrict__ bo2,
    const float* __restrict__ bo3,
    float* __restrict__ y)
{
    __shared__ u32 buf0[64 * 256];
    __shared__ u32 buf1[64 * 256];
    const int tid = threadIdx.x, lane = tid & 63, wv = tid >> 6;
    const size_t row0 = (size_t)blockIdx.x * 64;

    stage64(m + row0 * MOTOR, buf0, tid);
    __syncthreads();
    mfma_layer<MOTOR, H1,   true,  false>(Bpk + OFF_O1, bo1, buf0, buf1, nullptr, lane, wv);
    __syncthreads();
    mfma_layer<H1,    H1,   true,  false>(Bpk + OFF_O2, bo2, buf1, buf0, nullptr, lane, wv);
    __syncthreads();
    mfma_layer<H1,    DOUT, false, true >(Bpk + OFF_O3, bo3, buf0, nullptr, y + row0 * DOUT, lane, wv);
}

// ---------------------------------------------------------------------------
// RNN scan v10: shrink per-thread state so it FITS in arch VGPRs.
// 256 blocks x 1 sample, 1024 threads (16 waves, 4/SIMD).
//
// Rounds 8/9 evidence: 160 weight floats/thread > ~104 arch VGPRs -> half
// the weights lived in AGPRs; every FMA paid a v_accvgpr_read (VALU issue
// ~434 insts/wave/step vs ~160 FMA). asm re-pins only added shuttle copies.
// Structural fix: k-split 16 (s = tid&15 covers k in [16s,16s+16)), group
// g = tid>>4 owns h-rows {4g..4g+3} (o=0..3) and m-row g (o=4).
// -> 80 weight floats/thread + ~30 working regs < 128-VGPR cap
//    (__launch_bounds__(1024) => 4 waves/SIMD) : no AGPR traffic at all,
//    and 2x the waves for latency hiding.
// Partials: part[(5g+o)*20 + s]; the 16 writer lanes of a set and its
// reducer lane are the SAME 16-lane group = same wave -> DS-pipe ordering
// makes the exchange barrier-free (v7/v8-proven); sets are wave-private.
// Stride 20: collision-free, 16B-aligned for the 4 b128 reduce reads,
// <=4-way write aliasing. h-read rotation (ii+s)&3 keeps reads ~2-way.
// h double-buffered -> single __syncthreads per step.
// ---------------------------------------------------------------------------
__global__ __launch_bounds__(1024) void rnn_kernel(
    const float* __restrict__ u,      // [B*T, STATE]
    const float* __restrict__ WpT,    // [320][256] = [WhhT ; WhoT]
    const float* __restrict__ bo,     // [MOTOR]
    float* __restrict__ m)            // [B*T, MOTOR]
{
    __shared__ float hb[2][STATE];
    __shared__ float part[320 * 20];  // [p=5g+o][20] ; set uses words 0..15

    const int tid   = threadIdx.x;
    const int b     = blockIdx.x;
    const int s     = tid & 15;          // k-slice: [16s, 16s+16)
    const int g     = tid >> 4;          // 0..63
    const int kbase = s * 16;

    // --- weights -> registers (once), rotation baked in ---
    // o=0..3: Whh rows 4g+o ; o=4: Who row g (WpT row 256+g). 80 floats.
    float4 wq[5][4];
    #pragma unroll
    for (int o = 0; o < 5; ++o) {
        const int row = (o < 4) ? (4 * g + o) : (STATE + g);
        const float* wr = WpT + (size_t)row * STATE + kbase;
        #pragma unroll
        for (int ii = 0; ii < 4; ++ii)
            wq[o][ii] = *(const float4*)(wr + 4 * ((ii + s) & 3));
    }
    // one-shot pin: keeps loads hoisted out of the loop (v5-proven); the
    // in-loop variant added shuttle copies (v9) -- do NOT repeat per iter.
    #pragma unroll
    for (int o = 0; o < 5; ++o)
        asm volatile("" : "+v"(wq[o][0].x), "+v"(wq[o][0].y), "+v"(wq[o][0].z), "+v"(wq[o][0].w),
                          "+v"(wq[o][1].x), "+v"(wq[o][1].y), "+v"(wq[o][1].z), "+v"(wq[o][1].w),
                          "+v"(wq[o][2].x), "+v"(wq[o][2].y), "+v"(wq[o][2].z), "+v"(wq[o][2].w),
                          "+v"(wq[o][3].x), "+v"(wq[o][3].y), "+v"(wq[o][3].z), "+v"(wq[o][3].w));

    const bool ish  = (s < 4);           // reducer lane for h-row hidx
    const int  hidx = 4 * g + (s & 3);

    const float bov  = (s == 4) ? bo[g] : 0.f;
    const float* ubase = u + (size_t)b * TT * STATE + hidx;   // h lanes only
    float*       mst   = m + (size_t)b * TT * MOTOR + g;      // s==4 lane cursor

    if (tid < STATE) hb[0][tid] = 0.f;
    float up = ish ? ubase[0] : 0.f;   // u_0
    __syncthreads();

    for (int t = 0; t <= TT; ++t) {
        // prefetch u_{t+1}: consumed one full iteration later
        float upn = 0.f;
        if (ish && t + 1 < TT) upn = ubase[(size_t)(t + 1) * STATE];

        // --- combined GEMV partials (reads hb[t&1] = h_{t-1}) : 80 FMA ---
        float a0 = 0.f, a1 = 0.f, a2 = 0.f, a3 = 0.f, a4 = 0.f;
        {
            const float* hp = hb[t & 1] + kbase;
            #pragma unroll
            for (int ii = 0; ii < 4; ++ii) {
                float4 hv = *(const float4*)(hp + 4 * ((ii + s) & 3));
                a0 = fmaf(wq[0][ii].x, hv.x, a0); a0 = fmaf(wq[0][ii].y, hv.y, a0);
                a0 = fmaf(wq[0][ii].z, hv.z, a0); a0 = fmaf(wq[0][ii].w, hv.w, a0);
                a1 = fmaf(wq[1][ii].x, hv.x, a1); a1 = fmaf(wq[1][ii].y, hv.y, a1);
                a1 = fmaf(wq[1][ii].z, hv.z, a1); a1 = fmaf(wq[1][ii].w, hv.w, a1);
                a2 = fmaf(wq[2][ii].x, hv.x, a2); a2 = fmaf(wq[2][ii].y, hv.y, a2);
                a2 = fmaf(wq[2][ii].z, hv.z, a2); a2 = fmaf(wq[2][ii].w, hv.w, a2);
                a3 = fmaf(wq[3][ii].x, hv.x, a3); a3 = fmaf(wq[3][ii].y, hv.y, a3);
                a3 = fmaf(wq[3][ii].z, hv.z, a3); a3 = fmaf(wq[3][ii].w, hv.w, a3);
                a4 = fmaf(wq[4][ii].x, hv.x, a4); a4 = fmaf(wq[4][ii].y, hv.y, a4);
                a4 = fmaf(wq[4][ii].z, hv.z, a4); a4 = fmaf(wq[4][ii].w, hv.w, a4);
            }
        }

        // --- same-wave partial exchange (sets are wave-private) ---
        part[(5 * g + 0) * 20 + s] = a0;
        part[(5 * g + 1) * 20 + s] = a1;
        part[(5 * g + 2) * 20 + s] = a2;
        part[(5 * g + 3) * 20 + s] = a3;
        part[(5 * g + 4) * 20 + s] = a4;

        if (s < 5) {
            const int pb = (5 * g + s) * 20;
            float4 pA = *(const float4*)(part + pb);
            float4 pB = *(const float4*)(part + pb + 4);
            float4 pC = *(const float4*)(part + pb + 8);
            float4 pD = *(const float4*)(part + pb + 12);
            float v = (((pA.x + pA.y) + (pA.z + pA.w)) + ((pB.x + pB.y) + (pB.z + pB.w)))
                    + (((pC.x + pC.y) + (pC.z + pC.w)) + ((pD.x + pD.y) + (pD.z + pD.w)));
            if (ish) {
                if (t < TT) hb[(t + 1) & 1][hidx] = tanh_fast(v + up);  // h_t
            } else if (t > 0) {
                mst[0] = v + bov;    // m_{t-1} = Who . h_{t-1} + bo
                mst += MOTOR;
            }
        }
        __syncthreads();   // h_t visible; next iter rewrites hb[t&1] after this
        up = upn;
    }
}

// ---------------------------------------------------------------------------
extern "C" void kernel_launch(void* const* d_in, const int* in_sizes, int n_in,
                              void* d_out, int out_size, void* d_ws, size_t ws_size,
                              hipStream_t stream) {
    const float* x   = (const float*)d_in[0];
    const float* Wi1 = (const float*)d_in[1];
    const float* bi1 = (const float*)d_in[2];
    const float* Wi2 = (const float*)d_in[3];
    const float* bi2 = (const float*)d_in[4];
    const float* Wi3 = (const float*)d_in[5];
    const float* bi3 = (const float*)d_in[6];
    const float* Wih = (const float*)d_in[7];
    const float* Whh = (const float*)d_in[8];
    const float* bh  = (const float*)d_in[9];
    const float* Who = (const float*)d_in[10];
    const float* bo  = (const float*)d_in[11];
    const float* Wo1 = (const float*)d_in[12];
    const float* bo1 = (const float*)d_in[13];
    const float* Wo2 = (const float*)d_in[14];
    const float* bo2 = (const float*)d_in[15];
    const float* Wo3 = (const float*)d_in[16];
    const float* bo3 = (const float*)d_in[17];
    float* y = (float*)d_out;

    // workspace (floats): u | mbuf | WpT(320x256) | Bpk(u32)
    float* u    = (float*)d_ws;
    float* mbuf = u    + (size_t)BT * STATE;
    float* WpT  = mbuf + (size_t)BT * MOTOR;
    u32*   Bpk  = (u32*)(WpT + (size_t)(STATE + MOTOR) * STATE);

    int prep_items = BPK_TOTAL + STATE*STATE + STATE*MOTOR;
    prep_kernel<<<(prep_items + 255)/256, 256, 0, stream>>>(
        Wi1, Wi2, Wi3, Wih, Wo1, Wo2, Wo3, Whh, Who, Bpk, WpT);
    encoder_mfma<<<BT/64, 256, 0, stream>>>(x, Bpk, bi1, bi2, bi3, bh, u);
    rnn_kernel<<<BB, 1024, 0, stream>>>(u, WpT, bo, mbuf);
    decoder_mfma<<<BT/64, 256, 0, stream>>>(mbuf, Bpk, bo1, bo2, bo3, y);
}

// Round 11
// 736.167 us; speedup vs baseline: 1.2739x; 1.2739x over previous
//
#include <hip/hip_runtime.h>
#include <hip/hip_bf16.h>
#include <cstddef>

// Problem constants
#define BB    256
#define TT    512
#define DIN   64
#define H1    256
#define INTER 128
#define STATE 256
#define MOTOR 64
#define DOUT  32
#define BT    (BB*TT)   // 131072

typedef unsigned int u32;
typedef short short8 __attribute__((ext_vector_type(8)));
typedef float f32x4  __attribute__((ext_vector_type(4)));

// Packed-weight (hi/lo bf16 in one u32) fragment-order offsets, in u32 elems
#define OFF_I1 0         // Wi1: 64x256   -> 16384
#define OFF_I2 16384     // Wi2: 256x256  -> 65536
#define OFF_I3 81920     // Wi3: 256x128  -> 32768
#define OFF_IH 114688    // Wih: 128x256  -> 32768
#define OFF_O1 147456    // Wo1: 64x256   -> 16384
#define OFF_O2 163840    // Wo2: 256x256  -> 65536
#define OFF_O3 229376    // Wo3: 256x32   -> 8192
#define BPK_TOTAL 237568

__device__ __forceinline__ float tanh_fast(float x) {
    float e = __expf(2.0f * x);
    return 1.0f - 2.0f / (e + 1.0f);
}

__device__ __forceinline__ u32 f2u(float f){ union{float f; u32 u;} v; v.f=f; return v.u; }
__device__ __forceinline__ float u2f(u32 u){ union{u32 u; float f;} v; v.u=u; return v.f; }

// fp32 -> packed (hi bf16 in [15:0], residual-lo bf16 in [31:16]), RNE both.
__device__ __forceinline__ u32 packhl(float x) {
    u32 b  = f2u(x);
    u32 hi = (b + 0x7fffu + ((b >> 16) & 1u)) >> 16;
    float lo = x - u2f(hi << 16);
    u32 bl = f2u(lo);
    u32 l16 = (bl + 0x7fffu + ((bl >> 16) & 1u)) >> 16;
    return (hi & 0xffffu) | (l16 << 16);
}

// 8 packed u32 -> hi-frag / lo-frag (each 8 bf16 as short8)
__device__ __forceinline__ void unpack8(uint4 w0, uint4 w1, short8& hi, short8& lo) {
    union { u32 u[4]; short8 s; } H, L;
    H.u[0] = __builtin_amdgcn_perm(w0.y, w0.x, 0x05040100u);
    L.u[0] = __builtin_amdgcn_perm(w0.y, w0.x, 0x07060302u);
    H.u[1] = __builtin_amdgcn_perm(w0.w, w0.z, 0x05040100u);
    L.u[1] = __builtin_amdgcn_perm(w0.w, w0.z, 0x07060302u);
    H.u[2] = __builtin_amdgcn_perm(w1.y, w1.x, 0x05040100u);
    L.u[2] = __builtin_amdgcn_perm(w1.y, w1.x, 0x07060302u);
    H.u[3] = __builtin_amdgcn_perm(w1.w, w1.z, 0x05040100u);
    L.u[3] = __builtin_amdgcn_perm(w1.w, w1.z, 0x07060302u);
    hi = H.s; lo = L.s;
}

// LDS activation addressing: [64 rows][256 words], XOR-swizzled in 16B units.
__device__ __forceinline__ int swz(int row, int col) {
    return row * 256 + (col ^ ((row & 7) << 2));
}

// ---------------------------------------------------------------------------
// One MFMA MLP layer over a 64-token tile held in LDS (packed hi/lo u32).
//   Split-bf16: D += Ahi*Bhi + Ahi*Blo + Alo*Bhi  (~fp32 accuracy).
// ---------------------------------------------------------------------------
template<int K, int N, bool TANH, bool TOGLOBAL>
__device__ __forceinline__ void mfma_layer(
    const u32* __restrict__ Bpk, const float* __restrict__ bias,
    const u32* inB, u32* outB, float* __restrict__ gout,
    int lane, int wv)
{
    constexpr int NF  = N / 16;
    constexpr int NFW = (NF >= 4) ? NF / 4 : 1;
    constexpr int KC  = K / 32;
    const int q = lane >> 4, c = lane & 15;
    const int nf0 = wv * NFW;
    if (nf0 >= NF) return;   // small-N layers idle the upper waves

    f32x4 acc[4][NFW];
    #pragma unroll
    for (int nf = 0; nf < NFW; ++nf) {
        float bv = bias[(nf0 + nf) * 16 + c];
        #pragma unroll
        for (int rf = 0; rf < 4; ++rf) acc[rf][nf] = (f32x4){bv, bv, bv, bv};
    }

    #pragma unroll 2
    for (int kc = 0; kc < KC; ++kc) {
        short8 ahi[4], alo[4];
        #pragma unroll
        for (int rf = 0; rf < 4; ++rf) {
            int row = rf * 16 + c;
            int kb  = kc * 32 + q * 8;
            int m4  = (row & 7) << 2;
            uint4 w0 = *(const uint4*)(inB + row * 256 + ( kb      ^ m4));
            uint4 w1 = *(const uint4*)(inB + row * 256 + ((kb + 4) ^ m4));
            unpack8(w0, w1, ahi[rf], alo[rf]);
        }
        #pragma unroll
        for (int nf = 0; nf < NFW; ++nf) {
            const u32* bp = Bpk + (((size_t)(kc * NF + nf0 + nf) * 64 + lane) * 8);
            uint4 b0 = *(const uint4*)bp;
            uint4 b1 = *(const uint4*)(bp + 4);
            short8 bhi, blo; unpack8(b0, b1, bhi, blo);
            #pragma unroll
            for (int rf = 0; rf < 4; ++rf) {
                acc[rf][nf] = __builtin_amdgcn_mfma_f32_16x16x32_bf16(ahi[rf], bhi, acc[rf][nf], 0, 0, 0);
                acc[rf][nf] = __builtin_amdgcn_mfma_f32_16x16x32_bf16(ahi[rf], blo, acc[rf][nf], 0, 0, 0);
                acc[rf][nf] = __builtin_amdgcn_mfma_f32_16x16x32_bf16(alo[rf], bhi, acc[rf][nf], 0, 0, 0);
            }
        }
    }

    #pragma unroll
    for (int rf = 0; rf < 4; ++rf) {
        #pragma unroll
        for (int nf = 0; nf < NFW; ++nf) {
            #pragma unroll
            for (int r = 0; r < 4; ++r) {
                float v = acc[rf][nf][r];
                if (TANH) v = tanh_fast(v);
                int row = rf * 16 + q * 4 + r;
                int col = (nf0 + nf) * 16 + c;
                if (TOGLOBAL) gout[(size_t)row * N + col] = v;
                else          outB[swz(row, col)] = packhl(v);
            }
        }
    }
}

// Stage a [64 tokens][64 cols] fp32 global tile into packed LDS (cols 0..63).
__device__ __forceinline__ void stage64(const float* __restrict__ src, u32* dst, int tid) {
    int tt = tid >> 4;
    int c4 = (tid & 15) * 4;
    #pragma unroll
    for (int i = 0; i < 4; ++i) {
        int tok = tt + 16 * i;
        float4 v = *(const float4*)(src + (size_t)tok * 64 + c4);
        uint4 p;
        p.x = packhl(v.x); p.y = packhl(v.y); p.z = packhl(v.z); p.w = packhl(v.w);
        *(uint4*)(dst + swz(tok, c4)) = p;
    }
}

// ---------------------------------------------------------------------------
// prep: pack all MLP weights into MFMA-fragment order (hi/lo u32), and build
// WpT = [Whh^T (256 rows) ; Who^T (64 rows)], each row 256 floats.
// ---------------------------------------------------------------------------
__global__ __launch_bounds__(256) void prep_kernel(
    const float* __restrict__ Wi1, const float* __restrict__ Wi2,
    const float* __restrict__ Wi3, const float* __restrict__ Wih,
    const float* __restrict__ Wo1, const float* __restrict__ Wo2,
    const float* __restrict__ Wo3,
    const float* __restrict__ Whh, const float* __restrict__ Who,
    u32* __restrict__ Bpk, float* __restrict__ WpT)
{
    int idx = blockIdx.x * 256 + threadIdx.x;
    if (idx < BPK_TOTAL) {
        const float* W; int NF; int i = idx;
        if      (i < OFF_I2) { W = Wi1; NF = 16; i -= OFF_I1; }
        else if (i < OFF_I3) { W = Wi2; NF = 16; i -= OFF_I2; }
        else if (i < OFF_IH) { W = Wi3; NF = 8;  i -= OFF_I3; }
        else if (i < OFF_O1) { W = Wih; NF = 16; i -= OFF_IH; }
        else if (i < OFF_O2) { W = Wo1; NF = 16; i -= OFF_O1; }
        else if (i < OFF_O3) { W = Wo2; NF = 16; i -= OFF_O2; }
        else                 { W = Wo3; NF = 2;  i -= OFF_O3; }
        int e = i & 7, l = (i >> 3) & 63, t = i >> 9;
        int nf = t % NF, kc = t / NF;
        int k = kc * 32 + ((l >> 4) * 8) + e;
        int n = nf * 16 + (l & 15);
        Bpk[idx] = packhl(W[(size_t)k * (NF * 16) + n]);
    } else if (idx < BPK_TOTAL + STATE*STATE) {
        int i = idx - BPK_TOTAL; int j = i >> 8, n = i & 255;
        WpT[n * STATE + j] = Whh[j * STATE + n];
    } else if (idx < BPK_TOTAL + STATE*STATE + STATE*MOTOR) {
        int i = idx - BPK_TOTAL - STATE*STATE; int j = i >> 6, o = i & 63;
        WpT[(size_t)(STATE + o) * STATE + j] = Who[j * MOTOR + o];
    }
}

// ---------------------------------------------------------------------------
// MFMA encoder: x -> tanh(Wi1) -> tanh(Wi2) -> Wi3 -> (Wih + bh) = u
// ---------------------------------------------------------------------------
__global__ __launch_bounds__(256, 1) void encoder_mfma(
    const float* __restrict__ x, const u32* __restrict__ Bpk,
    const float* __restrict__ bi1, const float* __restrict__ bi2,
    const float* __restrict__ bi3, const float* __restrict__ bh,
    float* __restrict__ u)
{
    __shared__ u32 buf0[64 * 256];
    __shared__ u32 buf1[64 * 256];
    const int tid = threadIdx.x, lane = tid & 63, wv = tid >> 6;
    const size_t row0 = (size_t)blockIdx.x * 64;

    stage64(x + row0 * DIN, buf0, tid);
    __syncthreads();
    mfma_layer<DIN,  H1,    true,  false>(Bpk + OFF_I1, bi1, buf0, buf1, nullptr, lane, wv);
    __syncthreads();
    mfma_layer<H1,   H1,    true,  false>(Bpk + OFF_I2, bi2, buf1, buf0, nullptr, lane, wv);
    __syncthreads();
    mfma_layer<H1,   INTER, false, false>(Bpk + OFF_I3, bi3, buf0, buf1, nullptr, lane, wv);
    __syncthreads();
    mfma_layer<INTER,STATE, false, true >(Bpk + OFF_IH, bh,  buf1, nullptr, u + row0 * STATE, lane, wv);
}

// ---------------------------------------------------------------------------
// MFMA decoder: m -> tanh(Wo1) -> tanh(Wo2) -> Wo3 -> y
// ---------------------------------------------------------------------------
__global__ __launch_bounds__(256, 1) void decoder_mfma(
    const float* __restrict__ m, const u32* __restrict__ Bpk,
    const float* __restrict__ bo1, const float* __restrict__ bo2,
    const float* __restrict__ bo3,
    float* __restrict__ y)
{
    __shared__ u32 buf0[64 * 256];
    __shared__ u32 buf1[64 * 256];
    const int tid = threadIdx.x, lane = tid & 63, wv = tid >> 6;
    const size_t row0 = (size_t)blockIdx.x * 64;

    stage64(m + row0 * MOTOR, buf0, tid);
    __syncthreads();
    mfma_layer<MOTOR, H1,   true,  false>(Bpk + OFF_O1, bo1, buf0, buf1, nullptr, lane, wv);
    __syncthreads();
    mfma_layer<H1,    H1,   true,  false>(Bpk + OFF_O2, bo2, buf1, buf0, nullptr, lane, wv);
    __syncthreads();
    mfma_layer<H1,    DOUT, false, true >(Bpk + OFF_O3, bo3, buf0, nullptr, y + row0 * DOUT, lane, wv);
}

// ---------------------------------------------------------------------------
// RNN scan v11: v8 structure, NO asm pins, precomputed rotated h-pointers.
// 256 blocks x 1 sample, 512 threads (8 waves, 2/SIMD), 1 barrier/step.
//
// Evidence trail: v4 scratch-spill came from DIVERGENT weight init (fixed by
// uniform init in v5, which ALSO added asm pins). v3 (no pins) shows FETCH
// ~67MB -> pins were never needed to keep weights resident. v8/v9/v10 show
// VGPR_Count (104/104/60) scaling DOWN while the pins force values into "v"
// at 20 asm points -> live-range splits: weights homed in AGPR, shuttle
// copies at every use (VALUBusy 81%). v11 removes ALL pins.
//
// VALU diet: the 8 rotated h-read addresses per buffer are loop-invariant ->
// precompute pointer arrays hp0[8]/hp1[8]; loop 2x-unrolled so the buffer
// choice is compile-time (rule #20: all array indices static).
// Partials: part[g*44 + o*8 + s]: sets (8 words) never overlap (8*4+7=39<44),
// bases 16B-aligned (176g+32o bytes), writes ~2-way banked (12g+s mod 32).
// Same-wave exchange (16-lane groups never straddle waves at 512 threads);
// DS-pipe in-order per wave -> no barrier between write and read-back.
// ---------------------------------------------------------------------------
__global__ __launch_bounds__(512, 2) void rnn_kernel(
    const float* __restrict__ u,      // [B*T, STATE]
    const float* __restrict__ WpT,    // [320][256] = [WhhT ; WhoT]
    const float* __restrict__ bo,     // [MOTOR]
    float* __restrict__ m)            // [B*T, MOTOR]
{
    __shared__ float hb[2][STATE];
    __shared__ float part[64 * 44];   // [g][o][s] : g*44 + o*8 + s

    const int tid   = threadIdx.x;
    const int b     = blockIdx.x;
    const int s     = tid & 7;
    const int g     = tid >> 3;          // 0..63
    const int kbase = s * 32;

    // --- weights -> registers (once), UNIFORM shape/order across threads ---
    // o=0..3: Whh rows 4g+o ; o=4: Who row g (WpT row 256+g). 160 floats.
    float4 wq[5][8];
    #pragma unroll
    for (int o = 0; o < 5; ++o) {
        const int row = (o < 4) ? (4 * g + o) : (STATE + g);
        const float* wr = WpT + (size_t)row * STATE + kbase;
        #pragma unroll
        for (int ii = 0; ii < 8; ++ii)
            wq[o][ii] = *(const float4*)(wr + 4 * ((ii + s) & 7));
    }

    // --- precomputed rotated h-read pointers (both buffers) ---
    const float4* hp0[8];
    const float4* hp1[8];
    #pragma unroll
    for (int ii = 0; ii < 8; ++ii) {
        int off = kbase + 4 * ((ii + s) & 7);
        hp0[ii] = (const float4*)(hb[0] + off);
        hp1[ii] = (const float4*)(hb[1] + off);
    }

    const bool ish  = (s < 4);           // reducer lane for h-row hidx
    const int  hidx = 4 * g + (s & 3);
    const int  pb   = g * 44 + s * 8;    // set base this lane reduces (s<5)

    const float bov  = (s == 4) ? bo[g] : 0.f;
    const float* ubase = u + (size_t)b * TT * STATE + hidx;   // ish lanes
    float*       mst   = m + (size_t)b * TT * MOTOR + g;      // s==4 cursor

    if (tid < STATE) hb[0][tid] = 0.f;
    float up = ish ? ubase[0] : 0.f;   // u_0
    __syncthreads();

    // body: read h_{t-1} via HP (compile-time buffer), publish h_t to HWR.
#define RNN_BODY(T, HP, HWR)                                                   \
    {                                                                          \
        float upn = 0.f;                                                       \
        if (ish && (T) + 1 < TT) upn = ubase[(size_t)((T) + 1) * STATE];       \
        float a0 = 0.f, a1 = 0.f, a2 = 0.f, a3 = 0.f, a4 = 0.f;                \
        _Pragma("unroll")                                                      \
        for (int ii = 0; ii < 8; ++ii) {                                       \
            float4 hv = *HP[ii];                                               \
            a0 = fmaf(wq[0][ii].x, hv.x, a0); a0 = fmaf(wq[0][ii].y, hv.y, a0);\
            a0 = fmaf(wq[0][ii].z, hv.z, a0); a0 = fmaf(wq[0][ii].w, hv.w, a0);\
            a1 = fmaf(wq[1][ii].x, hv.x, a1); a1 = fmaf(wq[1][ii].y, hv.y, a1);\
            a1 = fmaf(wq[1][ii].z, hv.z, a1); a1 = fmaf(wq[1][ii].w, hv.w, a1);\
            a2 = fmaf(wq[2][ii].x, hv.x, a2); a2 = fmaf(wq[2][ii].y, hv.y, a2);\
            a2 = fmaf(wq[2][ii].z, hv.z, a2); a2 = fmaf(wq[2][ii].w, hv.w, a2);\
            a3 = fmaf(wq[3][ii].x, hv.x, a3); a3 = fmaf(wq[3][ii].y, hv.y, a3);\
            a3 = fmaf(wq[3][ii].z, hv.z, a3); a3 = fmaf(wq[3][ii].w, hv.w, a3);\
            a4 = fmaf(wq[4][ii].x, hv.x, a4); a4 = fmaf(wq[4][ii].y, hv.y, a4);\
            a4 = fmaf(wq[4][ii].z, hv.z, a4); a4 = fmaf(wq[4][ii].w, hv.w, a4);\
        }                                                                      \
        part[g * 44 +  0 + s] = a0;                                            \
        part[g * 44 +  8 + s] = a1;                                            \
        part[g * 44 + 16 + s] = a2;                                            \
        part[g * 44 + 24 + s] = a3;                                            \
        part[g * 44 + 32 + s] = a4;                                            \
        if (s < 5) {                                                           \
            float4 pA = *(const float4*)(part + pb);                           \
            float4 pB = *(const float4*)(part + pb + 4);                       \
            float v = ((pA.x + pA.y) + (pA.z + pA.w))                          \
                    + ((pB.x + pB.y) + (pB.z + pB.w));                         \
            if (ish) {                                                         \
                if ((T) < TT) HWR[hidx] = tanh_fast(v + up);                   \
            } else if ((T) > 0) {                                              \
                mst[0] = v + bov;                                              \
                mst += MOTOR;                                                  \
            }                                                                  \
        }                                                                      \
        __syncthreads();                                                       \
        up = upn;                                                              \
    }

    for (int t = 0; t <= TT; t += 2) {
        RNN_BODY(t,     hp0, (hb[1]));      // even t: read hb0, write hb1
        if (t + 1 <= TT)
            RNN_BODY(t + 1, hp1, (hb[0]));  // odd t: read hb1, write hb0
    }
#undef RNN_BODY
}

// ---------------------------------------------------------------------------
extern "C" void kernel_launch(void* const* d_in, const int* in_sizes, int n_in,
                              void* d_out, int out_size, void* d_ws, size_t ws_size,
                              hipStream_t stream) {
    const float* x   = (const float*)d_in[0];
    const float* Wi1 = (const float*)d_in[1];
    const float* bi1 = (const float*)d_in[2];
    const float* Wi2 = (const float*)d_in[3];
    const float* bi2 = (const float*)d_in[4];
    const float* Wi3 = (const float*)d_in[5];
    const float* bi3 = (const float*)d_in[6];
    const float* Wih = (const float*)d_in[7];
    const float* Whh = (const float*)d_in[8];
    const float* bh  = (const float*)d_in[9];
    const float* Who = (const float*)d_in[10];
    const float* bo  = (const float*)d_in[11];
    const float* Wo1 = (const float*)d_in[12];
    const float* bo1 = (const float*)d_in[13];
    const float* Wo2 = (const float*)d_in[14];
    const float* bo2 = (const float*)d_in[15];
    const float* Wo3 = (const float*)d_in[16];
    const float* bo3 = (const float*)d_in[17];
    float* y = (float*)d_out;

    // workspace (floats): u | mbuf | WpT(320x256) | Bpk(u32)
    float* u    = (float*)d_ws;
    float* mbuf = u    + (size_t)BT * STATE;
    float* WpT  = mbuf + (size_t)BT * MOTOR;
    u32*   Bpk  = (u32*)(WpT + (size_t)(STATE + MOTOR) * STATE);

    int prep_items = BPK_TOTAL + STATE*STATE + STATE*MOTOR;
    prep_kernel<<<(prep_items + 255)/256, 256, 0, stream>>>(
        Wi1, Wi2, Wi3, Wih, Wo1, Wo2, Wo3, Whh, Who, Bpk, WpT);
    encoder_mfma<<<BT/64, 256, 0, stream>>>(x, Bpk, bi1, bi2, bi3, bh, u);
    rnn_kernel<<<BB, 512, 0, stream>>>(u, WpT, bo, mbuf);
    decoder_mfma<<<BT/64, 256, 0, stream>>>(mbuf, Bpk, bo1, bo2, bo3, y);
}